// Round 8
// baseline (161.605 us; speedup 1.0000x reference)
//
#include <hip/hip_runtime.h>
#include <hip/hip_bf16.h>

typedef unsigned int uint;
typedef unsigned short ushort;
typedef unsigned long long ull;
typedef __attribute__((ext_vector_type(8))) short short8;
typedef __attribute__((ext_vector_type(4))) float float4_;

#define B_TOT 32768
#define NL    22
#define HID0  ((long)B_TOT * 20)

// ws layout (bytes), 16B aligned
#define W2F_OFF  0          // conv2 B-frags bf16 (k' = p*128+ic): 294,912
#define WFCF_OFF 294912     // fc    B-frags bf16: 65,536
#define WHF_OFF  360448     // heads B-frags bf16: 32,768
#define W1T_OFF  393216     // conv1 W^T f32: 550*128*4 = 281,600

// dynamic LDS: h1 chunk-major [144][33 rows][8 bf16] = 76,032 B (+pad row
// makes encode's scatter writes conflict-free; quarter-wave A-frag reads
// are contiguous) ; klist [4][64] uint at 76,032. total 77,056 B.
#define H1_LDS_BYTES 76032
#define LDS_TOTAL    77056

__device__ __forceinline__ ushort f2bf(float v) {
  uint x = __float_as_uint(v);
  x += 0x7fffu + ((x >> 16) & 1u);
  return (ushort)(x >> 16);
}
__device__ __forceinline__ uint cvtpk(float lo, float hi) {
  uint r;
  asm volatile("v_cvt_pk_bf16_f32 %0, %1, %2" : "=v"(r) : "v"(lo), "v"(hi));
  return r;
}

// ---------------- prologue: weight repack ----------------
extern "C" __global__ __launch_bounds__(256)
void k_prep(const float* __restrict__ wc1, const float* __restrict__ wc2,
            const float* __restrict__ wfc,
            const float* __restrict__ wa0, const float* __restrict__ wa1,
            const float* __restrict__ wv,
            ushort* __restrict__ w2f, ushort* __restrict__ wfcf,
            ushort* __restrict__ whf, float* __restrict__ w1t)
{
  int i = blockIdx.x * 256 + threadIdx.x;
  if (i < 18432) {            // conv2 B-frags, p-major k: k' = p*128 + ic
    int l = i & 63, cg = (i >> 6) & 7, ks = i >> 9;
    int col = cg * 16 + (l & 15), kb = ks * 32 + (l >> 4) * 8;
    ushort t[8];
    #pragma unroll
    for (int j = 0; j < 8; ++j) {
      int kp = kb + j, ic = kp & 127, p = kp >> 7;
      t[j] = f2bf(wc2[col * 1152 + ic * 9 + p]);
    }
    uint4 o = { (uint)t[0]|((uint)t[1]<<16), (uint)t[2]|((uint)t[3]<<16),
                (uint)t[4]|((uint)t[5]<<16), (uint)t[6]|((uint)t[7]<<16) };
    ((uint4*)w2f)[i] = o;
  } else if (i < 22528) {     // fc: B[k][col] = wfc[k][col]
    int i2 = i - 18432;
    int l = i2 & 63, cg = (i2 >> 6) & 15, ks = i2 >> 10;
    int col = cg * 16 + (l & 15), kb = ks * 32 + (l >> 4) * 8;
    ushort t[8];
    #pragma unroll
    for (int j = 0; j < 8; ++j) t[j] = f2bf(wfc[(kb + j) * 256 + col]);
    uint4 o = { (uint)t[0]|((uint)t[1]<<16), (uint)t[2]|((uint)t[3]<<16),
                (uint)t[4]|((uint)t[5]<<16), (uint)t[6]|((uint)t[7]<<16) };
    ((uint4*)wfcf)[i2] = o;
  } else if (i < 24576) {     // heads: cols 0..8 wa0, 9..18 wa1, 19 wv
    int i2 = i - 22528;
    int l = i2 & 63, cg = (i2 >> 6) & 1, ks = i2 >> 7;
    int col = cg * 16 + (l & 15), kb = ks * 32 + (l >> 4) * 8;
    ushort t[8];
    #pragma unroll
    for (int j = 0; j < 8; ++j) {
      int k = kb + j;
      float v = (col < 9)  ? wa0[k*9 + col]
              : (col < 19) ? wa1[k*10 + (col - 9)]
              : (col == 19) ? wv[k] : 0.f;
      t[j] = f2bf(v);
    }
    uint4 o = { (uint)t[0]|((uint)t[1]<<16), (uint)t[2]|((uint)t[3]<<16),
                (uint)t[4]|((uint)t[5]<<16), (uint)t[6]|((uint)t[7]<<16) };
    ((uint4*)whf)[i2] = o;
  } else if (i < 24576 + 70400) {   // w1t[r*128+oc] = wc1[oc][r]
    int j = i - 24576;
    int oc = j & 127, r = j >> 7;
    w1t[j] = wc1[oc * 550 + r];
  }
}

// ---------------- fused: encode + conv2 + fc + heads ----------------
// 32 samples/block, 256 threads (4 waves x 8 samples), h1 never leaves LDS.
extern "C" __global__ __launch_bounds__(256)
void k_main(const int* __restrict__ obs, const float* __restrict__ maxvec,
            const float* __restrict__ w1t, const float* __restrict__ bc1,
            const float* __restrict__ wself, const float* __restrict__ bself,
            const ushort* __restrict__ w2f, const float* __restrict__ bc2,
            const ushort* __restrict__ wfcf, const float* __restrict__ bfc,
            const ushort* __restrict__ whf,
            const float* __restrict__ ba0, const float* __restrict__ ba1,
            const float* __restrict__ bv, float* __restrict__ out)
{
  extern __shared__ char smem[];
  uint* h1w   = (uint*)smem;                    // [chunk][33 rows][4 uints]
  uint* klist = (uint*)(smem + H1_LDS_BYTES);   // [4][64]

  const int tid = threadIdx.x, lane = tid & 63, w = tid >> 6;
  const int lo = lane & 15, hi = lane >> 4;
  const int b0 = blockIdx.x * 32;

  float rm_own = (lane < NL) ? (1.0f / maxvec[lane]) : 0.f;
  const float2 bcp  = ((const float2*)bc1)[lane];
  const float2 bsp0 = ((const float2*)bself)[lane];
  const float2 bsp1 = ((const float2*)bself)[64 + lane];
  uint* kl = klist + w * 64;

  // ================= phase 1: encode (8 samples per wave) =================
  for (int s = 0; s < 8; ++s) {
    const int  r = w * 8 + s;
    const long b = b0 + r;
    const uint* ob = (const uint*)obs + b * 600;

    // decode + ordered compaction
    int cnt = 0;
    #pragma unroll
    for (int rr = 0; rr < 4; ++rr) {
      int m = rr * 64 + lane;
      bool valid = false; uint pk = 0;
      if (m < 200) {
        uint c = ob[m*3], a = ob[m*3+1], v = ob[m*3+2];
        c = (c == 255u) ? 0u : c;  a = (a == 255u) ? 0u : a;  v = (v == 255u) ? 0u : v;
        uint x = (c >> 4) & 15u, y = c & 15u;
        valid = (x < 11u) && (y < 11u) && (a < NL);
        pk = (a << 16) | (x << 12) | (y << 8) | v;
      }
      ull bal = __ballot(valid);
      if (valid) {
        int pos = cnt + __popcll(bal & ((1ull << lane) - 1ull));
        if (pos < 64) kl[pos] = pk;
      }
      cnt += __popcll(bal);
    }
    if (cnt > 64) cnt = 64;

    // dedup: last write wins (shfl ring)
    uint u = (lane < cnt) ? kl[lane] : 0xffffffffu;
    uint cell = u >> 8;
    bool alive = (lane < cnt);
    for (int d = 1; d < cnt; ++d) {
      uint oc_ = __shfl_down(cell, d);
      alive = alive && !((lane + d < cnt) && (oc_ == cell));
    }
    ull bal2 = __ballot(alive);
    const int n2 = __popcll(bal2);
    if (alive) kl[__popcll(bal2 & ((1ull << lane) - 1ull))] = u;

    // sparse conv1 + self head; token record is wave-uniform -> SGPRs
    float a0[9] = {0,0,0,0,0,0,0,0,0}, a1[9] = {0,0,0,0,0,0,0,0,0};
    float2 sa = {0.f,0.f}, sb = {0.f,0.f};
    uint nxt = kl[0];
    for (int t = 0; t < n2; ++t) {
      uint curv = nxt;
      nxt = kl[(t + 1) & 63];                         // prefetch
      uint cur = (uint)__builtin_amdgcn_readfirstlane((int)curv);
      int a = cur >> 16, x = (cur >> 12) & 15, y = (cur >> 8) & 15;
      float rmv = __int_as_float(
          __builtin_amdgcn_readlane(__float_as_int(rm_own), a));
      float fv = (float)(cur & 255u) * rmv;
      if (x == 5 && y == 5) {                         // scalar branch
        const float2* ws2 = (const float2*)(wself + a * 256);
        float2 w0 = ws2[lane], w1 = ws2[64 + lane];
        sa.x = fmaf(fv, w0.x, sa.x);  sa.y = fmaf(fv, w0.y, sa.y);
        sb.x = fmaf(fv, w1.x, sb.x);  sb.y = fmaf(fv, w1.y, sb.y);
      }
      #pragma unroll
      for (int ox = 0; ox < 3; ++ox) {
        int kx = x - 3 * ox;
        if ((unsigned)kx > 4u) continue;              // s_cmp + s_cbranch
        #pragma unroll
        for (int oy = 0; oy < 3; ++oy) {
          int ky = y - 3 * oy;
          if ((unsigned)ky > 4u) continue;
          int widx = a * 25 + kx * 5 + ky;            // scalar
          float2 wv2 = ((const float2*)w1t)[widx * 64 + lane];
          a0[ox*3+oy] = fmaf(fv, wv2.x, a0[ox*3+oy]);
          a1[ox*3+oy] = fmaf(fv, wv2.y, a1[ox*3+oy]);
        }
      }
    }

    // self_feat -> out hidden[:, 0:256]
    {
      float2 o0 = { fmaxf(sa.x + bsp0.x, 0.f), fmaxf(sa.y + bsp0.y, 0.f) };
      float2 o1 = { fmaxf(sb.x + bsp1.x, 0.f), fmaxf(sb.y + bsp1.y, 0.f) };
      float2* out2 = (float2*)(out + HID0 + b * 512);
      out2[lane] = o0;
      out2[64 + lane] = o1;
    }

    // h1 -> LDS, k' = p*128 + oc; lane's uint for p = (a0[p],a1[p]) pair.
    // chunk = p*16 + (lane>>2), dword-in-plane = r*4 + (lane&3); plane=132 dwords
    #pragma unroll
    for (int p = 0; p < 9; ++p) {
      uint val = cvtpk(fmaxf(a0[p] + bcp.x, 0.f), fmaxf(a1[p] + bcp.y, 0.f));
      h1w[(p * 16 + (lane >> 2)) * 132 + r * 4 + (lane & 3)] = val;
    }
  }
  __syncthreads();

  // ================= phase 2: conv2 via MFMA =================
  // A-frag: lane (lo,hi) reads chunk t*4+hi, row m*16+lo -> contiguous/quarter
  const short8* w2fv = (const short8*)w2f;
  float4_ acc[2][2];
  #pragma unroll
  for (int cgi = 0; cgi < 2; ++cgi) {
    float bv_ = bc2[(2*w + cgi)*16 + lo];
    float4_ t = {bv_, bv_, bv_, bv_};
    acc[0][cgi] = t; acc[1][cgi] = t;
  }
  for (int t = 0; t < 36; ++t) {
    const char* ap = smem + (size_t)(t*4 + hi) * 528;
    short8 af0 = *(const short8*)(ap + lo * 16);
    short8 af1 = *(const short8*)(ap + (16 + lo) * 16);
    #pragma unroll
    for (int cgi = 0; cgi < 2; ++cgi) {
      short8 bf = w2fv[(t*8 + 2*w + cgi)*64 + lane];
      acc[0][cgi] = __builtin_amdgcn_mfma_f32_16x16x32_bf16(af0, bf, acc[0][cgi], 0, 0, 0);
      acc[1][cgi] = __builtin_amdgcn_mfma_f32_16x16x32_bf16(af1, bf, acc[1][cgi], 0, 0, 0);
    }
  }
  __syncthreads();   // all h1 reads done -> safe to alias h2A over h1

  // ================= phase 3: h2 -> LDS (A-frag layout) =================
  ushort* h2A = (ushort*)smem;        // [16 chunks][32 rows][8]
  #pragma unroll
  for (int cgi = 0; cgi < 2; ++cgi) {
    int col = (2*w + cgi)*16 + lo;
    #pragma unroll
    for (int m = 0; m < 2; ++m)
      #pragma unroll
      for (int q = 0; q < 4; ++q) {
        int R = m*16 + hi*4 + q;
        h2A[((col >> 3) * 32 + R) * 8 + (col & 7)] =
            f2bf(fmaxf(acc[m][cgi][q], 0.f));
      }
  }
  __syncthreads();

  // ================= phase 4: fc via MFMA =================
  float4_ acc2[2][4];
  #pragma unroll
  for (int cgi = 0; cgi < 4; ++cgi) {
    float bv_ = bfc[(4*w + cgi)*16 + lo];
    float4_ t = {bv_, bv_, bv_, bv_};
    acc2[0][cgi] = t; acc2[1][cgi] = t;
  }
  const short8* wfcfv = (const short8*)wfcf;
  #pragma unroll
  for (int ks = 0; ks < 4; ++ks) {
    short8 af0 = *(const short8*)&h2A[((ks*4 + hi) * 32 + lo) * 8];
    short8 af1 = *(const short8*)&h2A[((ks*4 + hi) * 32 + 16 + lo) * 8];
    #pragma unroll
    for (int cgi = 0; cgi < 4; ++cgi) {
      short8 bf = wfcfv[(ks*16 + 4*w + cgi)*64 + lane];
      acc2[0][cgi] = __builtin_amdgcn_mfma_f32_16x16x32_bf16(af0, bf, acc2[0][cgi], 0, 0, 0);
      acc2[1][cgi] = __builtin_amdgcn_mfma_f32_16x16x32_bf16(af1, bf, acc2[1][cgi], 0, 0, 0);
    }
  }
  // cnn_feat -> out hidden[:, 256:512]
  #pragma unroll
  for (int cgi = 0; cgi < 4; ++cgi) {
    int col = (4*w + cgi)*16 + lo;
    #pragma unroll
    for (int m = 0; m < 2; ++m)
      #pragma unroll
      for (int q = 0; q < 4; ++q) {
        int R = m*16 + hi*4 + q;
        out[HID0 + (long)(b0 + R)*512 + 256 + col] = fmaxf(acc2[m][cgi][q], 0.f);
      }
  }
  __syncthreads();   // hidden rows b0..b0+31 visible block-wide

  // ================= phase 5: heads via MFMA =================
  const short8* whfv = (const short8*)whf;
  const int hm = w >> 1, hcg = w & 1;
  float4_ acc3;
  {
    int col = hcg*16 + lo;
    float bias = (col < 9) ? ba0[col] : (col < 19) ? ba1[col - 9]
               : (col == 19) ? bv[0] : 0.f;
    float4_ t = {bias, bias, bias, bias};
    acc3 = t;
  }
  const float* hrow = out + HID0 + (long)(b0 + hm*16 + lo) * 512;
  #pragma unroll
  for (int ks = 0; ks < 16; ++ks) {
    float4_ f0 = *(const float4_*)(hrow + ks*32 + hi*8);
    float4_ f1 = *(const float4_*)(hrow + ks*32 + hi*8 + 4);
    union { short8 s; ushort u[8]; } afu;
    afu.u[0] = f2bf(f0[0]); afu.u[1] = f2bf(f0[1]);
    afu.u[2] = f2bf(f0[2]); afu.u[3] = f2bf(f0[3]);
    afu.u[4] = f2bf(f1[0]); afu.u[5] = f2bf(f1[1]);
    afu.u[6] = f2bf(f1[2]); afu.u[7] = f2bf(f1[3]);
    short8 bf = whfv[(ks*2 + hcg)*64 + lane];
    acc3 = __builtin_amdgcn_mfma_f32_16x16x32_bf16(afu.s, bf, acc3, 0, 0, 0);
  }
  {
    int col = hcg*16 + lo;
    #pragma unroll
    for (int q = 0; q < 4; ++q) {
      long R = b0 + hm*16 + hi*4 + q;
      float v = acc3[q];
      if (col < 9)        out[R*9 + col] = v;
      else if (col < 19)  out[(long)B_TOT*9 + R*10 + (col - 9)] = v;
      else if (col == 19) out[(long)B_TOT*19 + R] = v;
    }
  }
}

extern "C" void kernel_launch(void* const* d_in, const int* in_sizes, int n_in,
                              void* d_out, int out_size, void* d_ws, size_t ws_size,
                              hipStream_t stream) {
  const int* obs      = (const int*)d_in[0];
  const float* maxvec = (const float*)d_in[1];
  const float* wc1    = (const float*)d_in[2];
  const float* bc1    = (const float*)d_in[3];
  const float* wc2    = (const float*)d_in[4];
  const float* bc2    = (const float*)d_in[5];
  const float* wfc    = (const float*)d_in[6];
  const float* bfc    = (const float*)d_in[7];
  const float* wself  = (const float*)d_in[8];
  const float* bself  = (const float*)d_in[9];
  const float* wa0    = (const float*)d_in[10];
  const float* ba0    = (const float*)d_in[11];
  const float* wa1    = (const float*)d_in[12];
  const float* ba1    = (const float*)d_in[13];
  const float* wv     = (const float*)d_in[14];
  const float* bv     = (const float*)d_in[15];
  float* out          = (float*)d_out;

  char* ws = (char*)d_ws;
  ushort* w2f  = (ushort*)(ws + W2F_OFF);
  ushort* wfcf = (ushort*)(ws + WFCF_OFF);
  ushort* whf  = (ushort*)(ws + WHF_OFF);
  float*  w1t  = (float*)(ws + W1T_OFF);

  hipFuncSetAttribute((const void*)k_main,
                      hipFuncAttributeMaxDynamicSharedMemorySize, LDS_TOTAL);

  k_prep<<<dim3(371),       dim3(256), 0, stream>>>(wc1, wc2, wfc, wa0, wa1, wv,
                                                    w2f, wfcf, whf, w1t);
  k_main<<<dim3(B_TOT/32),  dim3(256), LDS_TOTAL, stream>>>(
      obs, maxvec, w1t, bc1, wself, bself, w2f, bc2, wfcf, bfc,
      whf, ba0, ba1, bv, out);
}

// Round 9
// 118.858 us; speedup vs baseline: 1.3596x; 1.3596x over previous
//
#include <hip/hip_runtime.h>
#include <hip/hip_bf16.h>

typedef unsigned int uint;
typedef unsigned short ushort;
typedef unsigned long long ull;
typedef __attribute__((ext_vector_type(8))) short short8;
typedef __attribute__((ext_vector_type(4))) float float4_;

#define B_TOT 32768
#define NL    22
#define HID0  ((long)B_TOT * 20)

// ws layout (bytes), 16B aligned
#define W2F_OFF  0          // conv2 B-frags bf16 (k = ic*9+p): 294,912
#define WFCF_OFF 294912     // fc    B-frags bf16: 65,536
#define WHF_OFF  360448     // heads B-frags bf16: 32,768
#define W1P_OFF  393216     // conv1 W^T bf16-pairs: 550*64*4 = 140,800
#define H1_OFF   534016     // h1 row-major bf16: 32768*1152*2 = 75,497,472
// total 76,031,488

__device__ __forceinline__ ushort f2bf(float v) {
  uint x = __float_as_uint(v);
  x += 0x7fffu + ((x >> 16) & 1u);
  return (ushort)(x >> 16);
}
__device__ __forceinline__ uint cvtpk(float lo, float hi) {
  uint r;
  asm volatile("v_cvt_pk_bf16_f32 %0, %1, %2" : "=v"(r) : "v"(lo), "v"(hi));
  return r;
}

// ---------------- prologue: weight repack ----------------
extern "C" __global__ __launch_bounds__(256)
void k_prep(const float* __restrict__ wc1, const float* __restrict__ wc2,
            const float* __restrict__ wfc,
            const float* __restrict__ wa0, const float* __restrict__ wa1,
            const float* __restrict__ wv,
            ushort* __restrict__ w2f, ushort* __restrict__ wfcf,
            ushort* __restrict__ whf, uint* __restrict__ w1p)
{
  int i = blockIdx.x * 256 + threadIdx.x;
  if (i < 18432) {            // conv2 B-frags: B[k][col] = wc2[col][k], k = ic*9+p
    int l = i & 63, cg = (i >> 6) & 7, ks = i >> 9;
    int col = cg * 16 + (l & 15), kb = ks * 32 + (l >> 4) * 8;
    ushort t[8];
    #pragma unroll
    for (int j = 0; j < 8; ++j) t[j] = f2bf(wc2[col * 1152 + kb + j]);
    uint4 o = { (uint)t[0]|((uint)t[1]<<16), (uint)t[2]|((uint)t[3]<<16),
                (uint)t[4]|((uint)t[5]<<16), (uint)t[6]|((uint)t[7]<<16) };
    ((uint4*)w2f)[i] = o;
  } else if (i < 22528) {     // fc: B[k][col] = wfc[k][col]
    int i2 = i - 18432;
    int l = i2 & 63, cg = (i2 >> 6) & 15, ks = i2 >> 10;
    int col = cg * 16 + (l & 15), kb = ks * 32 + (l >> 4) * 8;
    ushort t[8];
    #pragma unroll
    for (int j = 0; j < 8; ++j) t[j] = f2bf(wfc[(kb + j) * 256 + col]);
    uint4 o = { (uint)t[0]|((uint)t[1]<<16), (uint)t[2]|((uint)t[3]<<16),
                (uint)t[4]|((uint)t[5]<<16), (uint)t[6]|((uint)t[7]<<16) };
    ((uint4*)wfcf)[i2] = o;
  } else if (i < 24576) {     // heads: cols 0..8 wa0, 9..18 wa1, 19 wv, 20..31 zero
    int i2 = i - 22528;
    int l = i2 & 63, cg = (i2 >> 6) & 1, ks = i2 >> 7;
    int col = cg * 16 + (l & 15), kb = ks * 32 + (l >> 4) * 8;
    ushort t[8];
    #pragma unroll
    for (int j = 0; j < 8; ++j) {
      int k = kb + j;
      float v = (col < 9)  ? wa0[k*9 + col]
              : (col < 19) ? wa1[k*10 + (col - 9)]
              : (col == 19) ? wv[k] : 0.f;
      t[j] = f2bf(v);
    }
    uint4 o = { (uint)t[0]|((uint)t[1]<<16), (uint)t[2]|((uint)t[3]<<16),
                (uint)t[4]|((uint)t[5]<<16), (uint)t[6]|((uint)t[7]<<16) };
    ((uint4*)whf)[i2] = o;
  } else if (i < 24576 + 35200) {   // w1p[r*64+l] = pack(wc1[2l][r], wc1[2l+1][r])
    int j = i - 24576;
    int l = j & 63, r = j >> 6;
    ushort lo_ = f2bf(wc1[(2*l)     * 550 + r]);
    ushort hi_ = f2bf(wc1[(2*l + 1) * 550 + r]);
    w1p[j] = (uint)lo_ | ((uint)hi_ << 16);
  }
}

// ---------------- kernel 1: tokens -> sparse conv1 + self head ----------------
// 1 wave per sample, 4 waves/block, no barriers, branch-free token loop.
extern "C" __global__ __launch_bounds__(256)
void k_encode(const int* __restrict__ obs, const float* __restrict__ maxvec,
              const uint* __restrict__ w1p, const float* __restrict__ bc1,
              const float* __restrict__ wself, const float* __restrict__ bself,
              float* __restrict__ out, ushort* __restrict__ h1g)
{
  __shared__ uint klist[4][64];

  const int tid = threadIdx.x, lane = tid & 63, w = tid >> 6;
  const long b = (long)blockIdx.x * 4 + w;

  float rm_own = (lane < NL) ? (1.0f / maxvec[lane]) : 0.f;

  // ---- decode + ordered compaction (direct global reads) ----
  const uint* ob = (const uint*)obs + b * 600;
  int cnt = 0;
  #pragma unroll
  for (int r = 0; r < 4; ++r) {
    int m = r * 64 + lane;
    bool valid = false; uint pk = 0;
    if (m < 200) {
      uint c = ob[m*3], a = ob[m*3+1], v = ob[m*3+2];
      c = (c == 255u) ? 0u : c;  a = (a == 255u) ? 0u : a;  v = (v == 255u) ? 0u : v;
      uint x = (c >> 4) & 15u, y = c & 15u;
      valid = (x < 11u) && (y < 11u) && (a < NL);
      pk = (a << 16) | (x << 12) | (y << 8) | v;
    }
    ull bal = __ballot(valid);
    if (valid) {
      int pos = cnt + __popcll(bal & ((1ull << lane) - 1ull));
      if (pos < 64) klist[w][pos] = pk;
    }
    cnt += __popcll(bal);
  }
  if (cnt > 64) cnt = 64;

  // ---- dedup (last write wins) via shfl ring scan ----
  uint u = (lane < cnt) ? klist[w][lane] : 0xffffffffu;
  uint cell = u >> 8;
  bool alive = (lane < cnt);
  for (int d = 1; d < cnt; ++d) {
    uint oc_ = __shfl_down(cell, d);
    alive = alive && !((lane + d < cnt) && (oc_ == cell));
  }
  ull bal2 = __ballot(alive);
  const int n2 = __popcll(bal2);
  if (alive) klist[w][__popcll(bal2 & ((1ull << lane) - 1ull))] = u;

  // ---- sparse conv1 (oc = 2*lane, 2*lane+1) + self head, branch-free ----
  // Token record scalarized (readfirstlane): address math in SALU, the 9
  // position loads issue unconditionally (clamped idx, masked fv) so they
  // pipeline instead of serializing under divergent branches.
  float a0[9] = {0,0,0,0,0,0,0,0,0}, a1[9] = {0,0,0,0,0,0,0,0,0};
  float2 sa = {0.f,0.f}, sb = {0.f,0.f};
  uint nxt = klist[w][0];
  for (int t = 0; t < n2; ++t) {
    uint curv = nxt;
    nxt = klist[w][(t + 1) & 63];                   // prefetch
    uint cur = (uint)__builtin_amdgcn_readfirstlane((int)curv);
    int a = cur >> 16, x = (cur >> 12) & 15, y = (cur >> 8) & 15;
    float rmv = __int_as_float(
        __builtin_amdgcn_readlane(__float_as_int(rm_own), a));
    float fv = (float)(cur & 255u) * rmv;
    if (x == 5 && y == 5) {                         // scalar (uniform) branch
      const float2* ws2 = (const float2*)(wself + a * 256);
      float2 w0 = ws2[lane], w1 = ws2[64 + lane];
      sa.x = fmaf(fv, w0.x, sa.x);  sa.y = fmaf(fv, w0.y, sa.y);
      sb.x = fmaf(fv, w1.x, sb.x);  sb.y = fmaf(fv, w1.y, sb.y);
    }
    const int wbase = a * 25;
    #pragma unroll
    for (int ox = 0; ox < 3; ++ox) {
      int kx = x - 3 * ox;
      #pragma unroll
      for (int oy = 0; oy < 3; ++oy) {
        int ky = y - 3 * oy;
        bool ok = ((unsigned)kx <= 4u) & ((unsigned)ky <= 4u);   // scalar
        int widx = ok ? (wbase + kx * 5 + ky) : 0;               // s_cselect
        uint wu = w1p[widx * 64 + lane];                         // always load
        float fvp = ok ? fv : 0.f;                               // 1 cndmask
        float wx = __uint_as_float(wu << 16);
        float wy = __uint_as_float(wu & 0xffff0000u);
        a0[ox*3+oy] = fmaf(fvp, wx, a0[ox*3+oy]);
        a1[ox*3+oy] = fmaf(fvp, wy, a1[ox*3+oy]);
      }
    }
  }

  // self_feat -> out hidden[:, 0:256]
  {
    const float2* bs2 = (const float2*)bself;
    float2 b0_ = bs2[lane], b1_ = bs2[64 + lane];
    float2 o0 = { fmaxf(sa.x + b0_.x, 0.f), fmaxf(sa.y + b0_.y, 0.f) };
    float2 o1 = { fmaxf(sb.x + b1_.x, 0.f), fmaxf(sb.y + b1_.y, 0.f) };
    float2* out2 = (float2*)(out + HID0 + b * 512);
    out2[lane] = o0;
    out2[64 + lane] = o1;
  }

  // h1 row-major [b][1152] bf16: lane's 18 values = words 9*lane..9*lane+8
  {
    const float2 bc = ((const float2*)bc1)[lane];
    float v0[9], v1[9];
    #pragma unroll
    for (int p = 0; p < 9; ++p) {
      v0[p] = fmaxf(a0[p] + bc.x, 0.f);
      v1[p] = fmaxf(a1[p] + bc.y, 0.f);
    }
    uint wds[9];
    wds[0] = cvtpk(v0[0], v0[1]);
    wds[1] = cvtpk(v0[2], v0[3]);
    wds[2] = cvtpk(v0[4], v0[5]);
    wds[3] = cvtpk(v0[6], v0[7]);
    wds[4] = cvtpk(v0[8], v1[0]);
    wds[5] = cvtpk(v1[1], v1[2]);
    wds[6] = cvtpk(v1[3], v1[4]);
    wds[7] = cvtpk(v1[5], v1[6]);
    wds[8] = cvtpk(v1[7], v1[8]);
    uint* dst = (uint*)h1g + b * 576 + 9 * lane;
    #pragma unroll
    for (int j = 0; j < 9; ++j) dst[j] = wds[j];
  }
}

// ---------------- kernel 2: conv2 + fc + heads via MFMA ----------------
extern "C" __global__ __launch_bounds__(256)
void k_mlp(const ushort* __restrict__ h1g, const ushort* __restrict__ w2f,
           const float* __restrict__ bc2, const ushort* __restrict__ wfcf,
           const float* __restrict__ bfc, const ushort* __restrict__ whf,
           const float* __restrict__ ba0, const float* __restrict__ ba1,
           const float* __restrict__ bv, float* __restrict__ out)
{
  __shared__ short  Abuf[2][4][64][8];   // 8 KB
  __shared__ ushort h2A[16][64][8];      // 16 KB

  const int tid = threadIdx.x, lane = tid & 63, w = tid >> 6;
  const int lo = lane & 15, hi = lane >> 4;
  const int bb = blockIdx.x, b0 = bb * 64;

  const short8* w2fv  = (const short8*)w2f;
  const short8* wfcfv = (const short8*)wfcf;
  const uint4*  A4    = (const uint4*)h1g;
  const long    arow  = (long)(b0 + (tid >> 2)) * 144 + (tid & 3);

  // ---- conv2: wave w owns cols (2w,2w+1)*16, all 64 rows ----
  float4_ acc[4][2];
  #pragma unroll
  for (int cgi = 0; cgi < 2; ++cgi) {
    float bv_ = bc2[(2*w + cgi)*16 + lo];
    float4_ t = {bv_, bv_, bv_, bv_};
    #pragma unroll
    for (int m = 0; m < 4; ++m) acc[m][cgi] = t;
  }

  uint4 rA = A4[arow];
  for (int t = 0; t < 36; ++t) {
    const int cur = t & 1;
    *(uint4*)&Abuf[cur][tid & 3][tid >> 2][0] = rA;
    if (t + 1 < 36) rA = A4[arow + (t + 1) * 4];
    __syncthreads();
    short8 af[4];
    #pragma unroll
    for (int m = 0; m < 4; ++m)
      af[m] = *(const short8*)&Abuf[cur][hi][m*16 + lo][0];
    #pragma unroll
    for (int cgi = 0; cgi < 2; ++cgi) {
      short8 bf = w2fv[(t*8 + 2*w + cgi)*64 + lane];
      #pragma unroll
      for (int m = 0; m < 4; ++m)
        acc[m][cgi] = __builtin_amdgcn_mfma_f32_16x16x32_bf16(af[m], bf, acc[m][cgi], 0, 0, 0);
    }
  }
  __syncthreads();

  // h2 -> LDS bf16 (A-frag layout)
  #pragma unroll
  for (int cgi = 0; cgi < 2; ++cgi) {
    int col = (2*w + cgi)*16 + lo;
    #pragma unroll
    for (int m = 0; m < 4; ++m)
      #pragma unroll
      for (int q = 0; q < 4; ++q) {
        int R = m*16 + hi*4 + q;
        h2A[col >> 3][R][col & 7] = f2bf(fmaxf(acc[m][cgi][q], 0.f));
      }
  }
  __syncthreads();

  // ---- fc: wave w owns cols (4w..4w+3)*16 ----
  float4_ acc2[4][4];
  #pragma unroll
  for (int cgi = 0; cgi < 4; ++cgi) {
    float bv_ = bfc[(4*w + cgi)*16 + lo];
    float4_ t = {bv_, bv_, bv_, bv_};
    #pragma unroll
    for (int m = 0; m < 4; ++m) acc2[m][cgi] = t;
  }
  #pragma unroll
  for (int ks = 0; ks < 4; ++ks) {
    short8 af[4];
    #pragma unroll
    for (int m = 0; m < 4; ++m)
      af[m] = *(const short8*)&h2A[ks*4 + hi][m*16 + lo][0];
    #pragma unroll
    for (int cgi = 0; cgi < 4; ++cgi) {
      short8 bf = wfcfv[(ks*16 + 4*w + cgi)*64 + lane];
      #pragma unroll
      for (int m = 0; m < 4; ++m)
        acc2[m][cgi] = __builtin_amdgcn_mfma_f32_16x16x32_bf16(af[m], bf, acc2[m][cgi], 0, 0, 0);
    }
  }

  // cnn_feat -> out hidden[:, 256:512]
  #pragma unroll
  for (int cgi = 0; cgi < 4; ++cgi) {
    int col = (4*w + cgi)*16 + lo;
    #pragma unroll
    for (int m = 0; m < 4; ++m)
      #pragma unroll
      for (int q = 0; q < 4; ++q) {
        int R = m*16 + hi*4 + q;
        out[HID0 + (long)(b0 + R)*512 + 256 + col] = fmaxf(acc2[m][cgi][q], 0.f);
      }
  }
  __syncthreads();   // drain stores; hidden rows b0..b0+63 visible block-wide

  // ---- heads: wave w owns rows w*16..w*16+15, cols 0..31 ----
  const short8* whfv = (const short8*)whf;
  float4_ acc3[2];
  #pragma unroll
  for (int cg = 0; cg < 2; ++cg) {
    int col = cg*16 + lo;
    float bias = (col < 9) ? ba0[col] : (col < 19) ? ba1[col - 9]
               : (col == 19) ? bv[0] : 0.f;
    float4_ t = {bias, bias, bias, bias};
    acc3[cg] = t;
  }

  const float* hrow = out + HID0 + (long)(b0 + w*16 + lo) * 512;
  #pragma unroll
  for (int ks = 0; ks < 16; ++ks) {
    float4_ f0 = *(const float4_*)(hrow + ks*32 + hi*8);
    float4_ f1 = *(const float4_*)(hrow + ks*32 + hi*8 + 4);
    union { short8 s; ushort u[8]; } afu;
    afu.u[0] = f2bf(f0[0]); afu.u[1] = f2bf(f0[1]);
    afu.u[2] = f2bf(f0[2]); afu.u[3] = f2bf(f0[3]);
    afu.u[4] = f2bf(f1[0]); afu.u[5] = f2bf(f1[1]);
    afu.u[6] = f2bf(f1[2]); afu.u[7] = f2bf(f1[3]);
    #pragma unroll
    for (int cg = 0; cg < 2; ++cg) {
      short8 bf = whfv[(ks*2 + cg)*64 + lane];
      acc3[cg] = __builtin_amdgcn_mfma_f32_16x16x32_bf16(afu.s, bf, acc3[cg], 0, 0, 0);
    }
  }

  #pragma unroll
  for (int cg = 0; cg < 2; ++cg) {
    int col = cg*16 + lo;
    #pragma unroll
    for (int q = 0; q < 4; ++q) {
      long R = b0 + w*16 + hi*4 + q;
      float v = acc3[cg][q];
      if (col < 9)        out[R*9 + col] = v;
      else if (col < 19)  out[(long)B_TOT*9 + R*10 + (col - 9)] = v;
      else if (col == 19) out[(long)B_TOT*19 + R] = v;
    }
  }
}

extern "C" void kernel_launch(void* const* d_in, const int* in_sizes, int n_in,
                              void* d_out, int out_size, void* d_ws, size_t ws_size,
                              hipStream_t stream) {
  const int* obs      = (const int*)d_in[0];
  const float* maxvec = (const float*)d_in[1];
  const float* wc1    = (const float*)d_in[2];
  const float* bc1    = (const float*)d_in[3];
  const float* wc2    = (const float*)d_in[4];
  const float* bc2    = (const float*)d_in[5];
  const float* wfc    = (const float*)d_in[6];
  const float* bfc    = (const float*)d_in[7];
  const float* wself  = (const float*)d_in[8];
  const float* bself  = (const float*)d_in[9];
  const float* wa0    = (const float*)d_in[10];
  const float* ba0    = (const float*)d_in[11];
  const float* wa1    = (const float*)d_in[12];
  const float* ba1    = (const float*)d_in[13];
  const float* wv     = (const float*)d_in[14];
  const float* bv     = (const float*)d_in[15];
  float* out          = (float*)d_out;

  char* ws = (char*)d_ws;
  ushort* w2f  = (ushort*)(ws + W2F_OFF);
  ushort* wfcf = (ushort*)(ws + WFCF_OFF);
  ushort* whf  = (ushort*)(ws + WHF_OFF);
  uint*   w1p  = (uint*)(ws + W1P_OFF);
  ushort* h1g  = (ushort*)(ws + H1_OFF);

  k_prep  <<<dim3(234),      dim3(256), 0, stream>>>(wc1, wc2, wfc, wa0, wa1, wv,
                                                     w2f, wfcf, whf, w1p);
  k_encode<<<dim3(B_TOT/4),  dim3(256), 0, stream>>>(obs, maxvec, w1p, bc1,
                                                     wself, bself, out, h1g);
  k_mlp   <<<dim3(B_TOT/64), dim3(256), 0, stream>>>(h1g, w2f, bc2, wfcf, bfc,
                                                     whf, ba0, ba1, bv, out);
}

// Round 10
// 105.202 us; speedup vs baseline: 1.5361x; 1.1298x over previous
//
#include <hip/hip_runtime.h>
#include <hip/hip_bf16.h>

typedef unsigned int uint;
typedef unsigned short ushort;
typedef unsigned long long ull;
typedef __attribute__((ext_vector_type(8))) short short8;
typedef __attribute__((ext_vector_type(4))) float float4_;

#define B_TOT 32768
#define NL    22
#define HID0  ((long)B_TOT * 20)

// ws layout (bytes), 16B aligned
#define W2F_OFF  0          // conv2 B-frags bf16 (k = ic*9+p): 294,912
#define WFCF_OFF 294912     // fc    B-frags bf16: 65,536
#define WHF_OFF  360448     // heads B-frags bf16: 32,768
#define W1P_OFF  393216     // conv1 W^T bf16-pairs: 550*64*4 = 140,800
#define H1_OFF   534016     // h1 row-major bf16: 32768*1152*2 = 75,497,472
// total 76,031,488

__device__ __forceinline__ ushort f2bf(float v) {
  uint x = __float_as_uint(v);
  x += 0x7fffu + ((x >> 16) & 1u);
  return (ushort)(x >> 16);
}
__device__ __forceinline__ uint cvtpk(float lo, float hi) {
  uint r;
  asm volatile("v_cvt_pk_bf16_f32 %0, %1, %2" : "=v"(r) : "v"(lo), "v"(hi));
  return r;
}
struct u3 { uint x, y, z; };

// ---------------- prologue: weight repack ----------------
extern "C" __global__ __launch_bounds__(256)
void k_prep(const float* __restrict__ wc1, const float* __restrict__ wc2,
            const float* __restrict__ wfc,
            const float* __restrict__ wa0, const float* __restrict__ wa1,
            const float* __restrict__ wv,
            ushort* __restrict__ w2f, ushort* __restrict__ wfcf,
            ushort* __restrict__ whf, uint* __restrict__ w1p)
{
  int i = blockIdx.x * 256 + threadIdx.x;
  if (i < 18432) {            // conv2 B-frags: B[k][col] = wc2[col][k], k = ic*9+p
    int l = i & 63, cg = (i >> 6) & 7, ks = i >> 9;
    int col = cg * 16 + (l & 15), kb = ks * 32 + (l >> 4) * 8;
    ushort t[8];
    #pragma unroll
    for (int j = 0; j < 8; ++j) t[j] = f2bf(wc2[col * 1152 + kb + j]);
    uint4 o = { (uint)t[0]|((uint)t[1]<<16), (uint)t[2]|((uint)t[3]<<16),
                (uint)t[4]|((uint)t[5]<<16), (uint)t[6]|((uint)t[7]<<16) };
    ((uint4*)w2f)[i] = o;
  } else if (i < 22528) {     // fc: B[k][col] = wfc[k][col]
    int i2 = i - 18432;
    int l = i2 & 63, cg = (i2 >> 6) & 15, ks = i2 >> 10;
    int col = cg * 16 + (l & 15), kb = ks * 32 + (l >> 4) * 8;
    ushort t[8];
    #pragma unroll
    for (int j = 0; j < 8; ++j) t[j] = f2bf(wfc[(kb + j) * 256 + col]);
    uint4 o = { (uint)t[0]|((uint)t[1]<<16), (uint)t[2]|((uint)t[3]<<16),
                (uint)t[4]|((uint)t[5]<<16), (uint)t[6]|((uint)t[7]<<16) };
    ((uint4*)wfcf)[i2] = o;
  } else if (i < 24576) {     // heads: cols 0..8 wa0, 9..18 wa1, 19 wv, 20..31 zero
    int i2 = i - 22528;
    int l = i2 & 63, cg = (i2 >> 6) & 1, ks = i2 >> 7;
    int col = cg * 16 + (l & 15), kb = ks * 32 + (l >> 4) * 8;
    ushort t[8];
    #pragma unroll
    for (int j = 0; j < 8; ++j) {
      int k = kb + j;
      float v = (col < 9)  ? wa0[k*9 + col]
              : (col < 19) ? wa1[k*10 + (col - 9)]
              : (col == 19) ? wv[k] : 0.f;
      t[j] = f2bf(v);
    }
    uint4 o = { (uint)t[0]|((uint)t[1]<<16), (uint)t[2]|((uint)t[3]<<16),
                (uint)t[4]|((uint)t[5]<<16), (uint)t[6]|((uint)t[7]<<16) };
    ((uint4*)whf)[i2] = o;
  } else if (i < 24576 + 35200) {   // w1p[r*64+l] = pack(wc1[2l][r], wc1[2l+1][r])
    int j = i - 24576;
    int l = j & 63, r = j >> 6;
    ushort lo_ = f2bf(wc1[(2*l)     * 550 + r]);
    ushort hi_ = f2bf(wc1[(2*l + 1) * 550 + r]);
    w1p[j] = (uint)lo_ | ((uint)hi_ << 16);
  }
}

// ---------------- kernel 1: tokens -> sparse conv1 + self head ----------------
// 1 wave per sample; token record scalarized -> ALL position conditionality
// on the scalar pipe (s_cmp/s_cbranch), no exec churn, no wasted loads.
extern "C" __global__ __launch_bounds__(256)
void k_encode(const int* __restrict__ obs, const float* __restrict__ maxvec,
              const uint* __restrict__ w1p, const float* __restrict__ bc1,
              const float* __restrict__ wself, const float* __restrict__ bself,
              float* __restrict__ out, ushort* __restrict__ h1g)
{
  __shared__ uint klist[4][64];

  const int tid = threadIdx.x, lane = tid & 63, w = tid >> 6;
  const long b = (long)blockIdx.x * 4 + w;

  float rm_own = (lane < NL) ? (1.0f / maxvec[lane]) : 0.f;

  // ---- decode + ordered compaction (one dwordx3 per token) ----
  const uint* ob = (const uint*)obs + b * 600;
  int cnt = 0;
  #pragma unroll
  for (int r = 0; r < 4; ++r) {
    int m = r * 64 + lane;
    bool valid = false; uint pk = 0;
    if (m < 200) {
      u3 tv = *(const u3*)(ob + m * 3);
      uint c = tv.x, a = tv.y, v = tv.z;
      c = (c == 255u) ? 0u : c;  a = (a == 255u) ? 0u : a;  v = (v == 255u) ? 0u : v;
      uint x = (c >> 4) & 15u, y = c & 15u;
      valid = (x < 11u) && (y < 11u) && (a < NL);
      pk = (a << 16) | (x << 12) | (y << 8) | v;
    }
    ull bal = __ballot(valid);
    if (valid) {
      int pos = cnt + __popcll(bal & ((1ull << lane) - 1ull));
      if (pos < 64) klist[w][pos] = pk;
    }
    cnt += __popcll(bal);
  }
  if (cnt > 64) cnt = 64;

  // ---- dedup (last write wins) via shfl ring scan ----
  uint u = (lane < cnt) ? klist[w][lane] : 0xffffffffu;
  uint cell = u >> 8;
  bool alive = (lane < cnt);
  for (int d = 1; d < cnt; ++d) {
    uint oc_ = __shfl_down(cell, d);
    alive = alive && !((lane + d < cnt) && (oc_ == cell));
  }
  ull bal2 = __ballot(alive);
  const int n2 = __popcll(bal2);
  if (alive) klist[w][__popcll(bal2 & ((1ull << lane) - 1ull))] = u;

  // ---- sparse conv1 (oc = 2*lane, 2*lane+1) + self head ----
  // Scalar token record + scalar position branches: skipped positions cost
  // 2 SALU, executed positions 1 load + 6 VALU. Accumulator indices stay
  // compile-time (rule #20).
  float a0[9] = {0,0,0,0,0,0,0,0,0}, a1[9] = {0,0,0,0,0,0,0,0,0};
  float2 sa = {0.f,0.f}, sb = {0.f,0.f};
  uint nxt = klist[w][0];
  for (int t = 0; t < n2; ++t) {
    uint curv = nxt;
    nxt = klist[w][(t + 1) & 63];                   // prefetch
    uint cur = (uint)__builtin_amdgcn_readfirstlane((int)curv);
    int a = cur >> 16, x = (cur >> 12) & 15, y = (cur >> 8) & 15;
    float rmv = __int_as_float(
        __builtin_amdgcn_readlane(__float_as_int(rm_own), a));
    float fv = (float)(cur & 255u) * rmv;
    if (x == 5 && y == 5) {                         // scalar branch
      const float2* ws2 = (const float2*)(wself + a * 256);
      float2 w0 = ws2[lane], w1 = ws2[64 + lane];
      sa.x = fmaf(fv, w0.x, sa.x);  sa.y = fmaf(fv, w0.y, sa.y);
      sb.x = fmaf(fv, w1.x, sb.x);  sb.y = fmaf(fv, w1.y, sb.y);
    }
    const int wbase = a * 25;
    #pragma unroll
    for (int ox = 0; ox < 3; ++ox) {
      int kx = x - 3 * ox;
      if ((unsigned)kx > 4u) continue;              // s_cmp + s_cbranch
      #pragma unroll
      for (int oy = 0; oy < 3; ++oy) {
        int ky = y - 3 * oy;
        if ((unsigned)ky > 4u) continue;            // s_cmp + s_cbranch
        uint wu = w1p[(wbase + kx * 5 + ky) * 64 + lane];
        float wx = __uint_as_float(wu << 16);
        float wy = __uint_as_float(wu & 0xffff0000u);
        a0[ox*3+oy] = fmaf(fv, wx, a0[ox*3+oy]);
        a1[ox*3+oy] = fmaf(fv, wy, a1[ox*3+oy]);
      }
    }
  }

  // self_feat -> out hidden[:, 0:256]
  {
    const float2* bs2 = (const float2*)bself;
    float2 b0_ = bs2[lane], b1_ = bs2[64 + lane];
    float2 o0 = { fmaxf(sa.x + b0_.x, 0.f), fmaxf(sa.y + b0_.y, 0.f) };
    float2 o1 = { fmaxf(sb.x + b1_.x, 0.f), fmaxf(sb.y + b1_.y, 0.f) };
    float2* out2 = (float2*)(out + HID0 + b * 512);
    out2[lane] = o0;
    out2[64 + lane] = o1;
  }

  // h1 row-major [b][1152] bf16: lane's 18 values = words 9*lane..9*lane+8
  {
    const float2 bc = ((const float2*)bc1)[lane];
    float v0[9], v1[9];
    #pragma unroll
    for (int p = 0; p < 9; ++p) {
      v0[p] = fmaxf(a0[p] + bc.x, 0.f);
      v1[p] = fmaxf(a1[p] + bc.y, 0.f);
    }
    uint wds[9];
    wds[0] = cvtpk(v0[0], v0[1]);
    wds[1] = cvtpk(v0[2], v0[3]);
    wds[2] = cvtpk(v0[4], v0[5]);
    wds[3] = cvtpk(v0[6], v0[7]);
    wds[4] = cvtpk(v0[8], v1[0]);
    wds[5] = cvtpk(v1[1], v1[2]);
    wds[6] = cvtpk(v1[3], v1[4]);
    wds[7] = cvtpk(v1[5], v1[6]);
    wds[8] = cvtpk(v1[7], v1[8]);
    uint* dst = (uint*)h1g + b * 576 + 9 * lane;
    #pragma unroll
    for (int j = 0; j < 9; ++j) dst[j] = wds[j];
  }
}

// ---------------- kernel 2: conv2 + fc + heads via MFMA ----------------
extern "C" __global__ __launch_bounds__(256)
void k_mlp(const ushort* __restrict__ h1g, const ushort* __restrict__ w2f,
           const float* __restrict__ bc2, const ushort* __restrict__ wfcf,
           const float* __restrict__ bfc, const ushort* __restrict__ whf,
           const float* __restrict__ ba0, const float* __restrict__ ba1,
           const float* __restrict__ bv, float* __restrict__ out)
{
  __shared__ short  Abuf[2][4][64][8];   // 8 KB
  __shared__ ushort h2A[16][64][8];      // 16 KB

  const int tid = threadIdx.x, lane = tid & 63, w = tid >> 6;
  const int lo = lane & 15, hi = lane >> 4;
  const int bb = blockIdx.x, b0 = bb * 64;

  const short8* w2fv  = (const short8*)w2f;
  const short8* wfcfv = (const short8*)wfcf;
  const uint4*  A4    = (const uint4*)h1g;
  const long    arow  = (long)(b0 + (tid >> 2)) * 144 + (tid & 3);

  // ---- conv2: wave w owns cols (2w,2w+1)*16, all 64 rows ----
  float4_ acc[4][2];
  #pragma unroll
  for (int cgi = 0; cgi < 2; ++cgi) {
    float bv_ = bc2[(2*w + cgi)*16 + lo];
    float4_ t = {bv_, bv_, bv_, bv_};
    #pragma unroll
    for (int m = 0; m < 4; ++m) acc[m][cgi] = t;
  }

  uint4 rA = A4[arow];
  for (int t = 0; t < 36; ++t) {
    const int cur = t & 1;
    *(uint4*)&Abuf[cur][tid & 3][tid >> 2][0] = rA;
    if (t + 1 < 36) rA = A4[arow + (t + 1) * 4];
    __syncthreads();
    short8 af[4];
    #pragma unroll
    for (int m = 0; m < 4; ++m)
      af[m] = *(const short8*)&Abuf[cur][hi][m*16 + lo][0];
    #pragma unroll
    for (int cgi = 0; cgi < 2; ++cgi) {
      short8 bf = w2fv[(t*8 + 2*w + cgi)*64 + lane];
      #pragma unroll
      for (int m = 0; m < 4; ++m)
        acc[m][cgi] = __builtin_amdgcn_mfma_f32_16x16x32_bf16(af[m], bf, acc[m][cgi], 0, 0, 0);
    }
  }
  __syncthreads();

  // h2 -> LDS bf16 (A-frag layout)
  #pragma unroll
  for (int cgi = 0; cgi < 2; ++cgi) {
    int col = (2*w + cgi)*16 + lo;
    #pragma unroll
    for (int m = 0; m < 4; ++m)
      #pragma unroll
      for (int q = 0; q < 4; ++q) {
        int R = m*16 + hi*4 + q;
        h2A[col >> 3][R][col & 7] = f2bf(fmaxf(acc[m][cgi][q], 0.f));
      }
  }
  __syncthreads();

  // ---- fc: wave w owns cols (4w..4w+3)*16 ----
  float4_ acc2[4][4];
  #pragma unroll
  for (int cgi = 0; cgi < 4; ++cgi) {
    float bv_ = bfc[(4*w + cgi)*16 + lo];
    float4_ t = {bv_, bv_, bv_, bv_};
    #pragma unroll
    for (int m = 0; m < 4; ++m) acc2[m][cgi] = t;
  }
  #pragma unroll
  for (int ks = 0; ks < 4; ++ks) {
    short8 af[4];
    #pragma unroll
    for (int m = 0; m < 4; ++m)
      af[m] = *(const short8*)&h2A[ks*4 + hi][m*16 + lo][0];
    #pragma unroll
    for (int cgi = 0; cgi < 4; ++cgi) {
      short8 bf = wfcfv[(ks*16 + 4*w + cgi)*64 + lane];
      #pragma unroll
      for (int m = 0; m < 4; ++m)
        acc2[m][cgi] = __builtin_amdgcn_mfma_f32_16x16x32_bf16(af[m], bf, acc2[m][cgi], 0, 0, 0);
    }
  }

  // cnn_feat -> out hidden[:, 256:512]
  #pragma unroll
  for (int cgi = 0; cgi < 4; ++cgi) {
    int col = (4*w + cgi)*16 + lo;
    #pragma unroll
    for (int m = 0; m < 4; ++m)
      #pragma unroll
      for (int q = 0; q < 4; ++q) {
        int R = m*16 + hi*4 + q;
        out[HID0 + (long)(b0 + R)*512 + 256 + col] = fmaxf(acc2[m][cgi][q], 0.f);
      }
  }
  __syncthreads();   // drain stores; hidden rows b0..b0+63 visible block-wide

  // ---- heads: wave w owns rows w*16..w*16+15, cols 0..31 ----
  const short8* whfv = (const short8*)whf;
  float4_ acc3[2];
  #pragma unroll
  for (int cg = 0; cg < 2; ++cg) {
    int col = cg*16 + lo;
    float bias = (col < 9) ? ba0[col] : (col < 19) ? ba1[col - 9]
               : (col == 19) ? bv[0] : 0.f;
    float4_ t = {bias, bias, bias, bias};
    acc3[cg] = t;
  }

  const float* hrow = out + HID0 + (long)(b0 + w*16 + lo) * 512;
  #pragma unroll
  for (int ks = 0; ks < 16; ++ks) {
    float4_ f0 = *(const float4_*)(hrow + ks*32 + hi*8);
    float4_ f1 = *(const float4_*)(hrow + ks*32 + hi*8 + 4);
    union { short8 s; ushort u[8]; } afu;
    afu.u[0] = f2bf(f0[0]); afu.u[1] = f2bf(f0[1]);
    afu.u[2] = f2bf(f0[2]); afu.u[3] = f2bf(f0[3]);
    afu.u[4] = f2bf(f1[0]); afu.u[5] = f2bf(f1[1]);
    afu.u[6] = f2bf(f1[2]); afu.u[7] = f2bf(f1[3]);
    #pragma unroll
    for (int cg = 0; cg < 2; ++cg) {
      short8 bf = whfv[(ks*2 + cg)*64 + lane];
      acc3[cg] = __builtin_amdgcn_mfma_f32_16x16x32_bf16(afu.s, bf, acc3[cg], 0, 0, 0);
    }
  }

  #pragma unroll
  for (int cg = 0; cg < 2; ++cg) {
    int col = cg*16 + lo;
    #pragma unroll
    for (int q = 0; q < 4; ++q) {
      long R = b0 + w*16 + hi*4 + q;
      float v = acc3[cg][q];
      if (col < 9)        out[R*9 + col] = v;
      else if (col < 19)  out[(long)B_TOT*9 + R*10 + (col - 9)] = v;
      else if (col == 19) out[(long)B_TOT*19 + R] = v;
    }
  }
}

extern "C" void kernel_launch(void* const* d_in, const int* in_sizes, int n_in,
                              void* d_out, int out_size, void* d_ws, size_t ws_size,
                              hipStream_t stream) {
  const int* obs      = (const int*)d_in[0];
  const float* maxvec = (const float*)d_in[1];
  const float* wc1    = (const float*)d_in[2];
  const float* bc1    = (const float*)d_in[3];
  const float* wc2    = (const float*)d_in[4];
  const float* bc2    = (const float*)d_in[5];
  const float* wfc    = (const float*)d_in[6];
  const float* bfc    = (const float*)d_in[7];
  const float* wself  = (const float*)d_in[8];
  const float* bself  = (const float*)d_in[9];
  const float* wa0    = (const float*)d_in[10];
  const float* ba0    = (const float*)d_in[11];
  const float* wa1    = (const float*)d_in[12];
  const float* ba1    = (const float*)d_in[13];
  const float* wv     = (const float*)d_in[14];
  const float* bv     = (const float*)d_in[15];
  float* out          = (float*)d_out;

  char* ws = (char*)d_ws;
  ushort* w2f  = (ushort*)(ws + W2F_OFF);
  ushort* wfcf = (ushort*)(ws + WFCF_OFF);
  ushort* whf  = (ushort*)(ws + WHF_OFF);
  uint*   w1p  = (uint*)(ws + W1P_OFF);
  ushort* h1g  = (ushort*)(ws + H1_OFF);

  k_prep  <<<dim3(234),      dim3(256), 0, stream>>>(wc1, wc2, wfc, wa0, wa1, wv,
                                                     w2f, wfcf, whf, w1p);
  k_encode<<<dim3(B_TOT/4),  dim3(256), 0, stream>>>(obs, maxvec, w1p, bc1,
                                                     wself, bself, out, h1g);
  k_mlp   <<<dim3(B_TOT/64), dim3(256), 0, stream>>>(h1g, w2f, bc2, wfcf, bfc,
                                                     whf, ba0, ba1, bv, out);
}